// Round 4
// baseline (1178.627 us; speedup 1.0000x reference)
//
#include <hip/hip_runtime.h>
#include <math.h>

// DownConvFace: 3 stages of {mesh_conv -> BN(global stats) -> (+res) -> LeakyReLU(0.2)}
// B=4, F=50000, Cin=32/64/64, O=64, fp32 in/out.
//
// R4: (1) chunk-major LDS layout for G (chunk stride 1056 B == 8 mod 32 dwords,
// rotated writes) -> 2-way max bank aliasing (free) instead of 8-way;
// (2) BN stats fused into conv epilogue via LDS tile round-trip (deterministic
// per-block partials), Y stored bf16 -> stats kernels + fp32 bufY eliminated.

typedef __attribute__((ext_vector_type(8))) short short8;
typedef __attribute__((ext_vector_type(8))) unsigned short ushort8_t;
typedef __attribute__((ext_vector_type(4))) float f32x4;

__device__ inline unsigned short f2bf(float v) {
    union { float f; unsigned u; } x; x.f = v;
    unsigned r = x.u + 0x7fffu + ((x.u >> 16) & 1u);   // RNE
    return (unsigned short)(r >> 16);
}
__device__ inline float bf2f(unsigned short u) {
    union { unsigned u; float f; } x; x.u = ((unsigned)u) << 16; return x.f;
}

// fe [B][32][F] fp32 -> fe_t [B][F][32] bf16. grid (ceil(F/64), B), block 256.
__global__ void transpose_fe_kernel(const float* __restrict__ fe,
                                    unsigned short* __restrict__ o, int F)
{
    __shared__ float tile[64 * 33];
    const int b = blockIdx.y;
    const int f0 = blockIdx.x * 64;
    const int t = threadIdx.x;
    const int lane = t & 63;
    const int w = t >> 6;
    const int f = f0 + lane;
    if (f < F) {
#pragma unroll
        for (int i = 0; i < 8; ++i) {
            const int c = w * 8 + i;
            tile[lane * 33 + c] = fe[((size_t)b * 32 + c) * F + f];
        }
    }
    __syncthreads();
    const int j = t >> 2, s = t & 3;
    const int fj = f0 + j;
    if (fj < F) {
        ushort8_t v;
#pragma unroll
        for (int i = 0; i < 8; ++i) v[i] = f2bf(tile[j * 33 + s * 8 + i]);
        *(ushort8_t*)(o + ((size_t)b * F + fj) * 32 + s * 8) = v;
    }
}

// Cast weights fp32->bf16 (flat; [O][C][4] == [O][4C], k=4c+kk).
__global__ void cast_weights_kernel(const float* __restrict__ w1,
                                    const float* __restrict__ w2a,
                                    const float* __restrict__ w2b,
                                    unsigned short* __restrict__ w1b,
                                    unsigned short* __restrict__ w2ab,
                                    unsigned short* __restrict__ w2bb)
{
    const int i = blockIdx.x * blockDim.x + threadIdx.x;
    if (i < 64 * 128) w1b[i] = f2bf(w1[i]);
    if (i < 64 * 256) { w2ab[i] = f2bf(w2a[i]); w2bb[i] = f2bf(w2b[i]); }
}

// Fused mesh-conv GEMM + BN-stats epilogue. Block 256 (4 waves), 64 faces x 64 o.
// grid = (ceil(F/64), B). Y out bf16 [B*F][64]; per-block stats partials to pS/pQ.
// G LDS layout: chunk kc (8 shorts) at short-offset kc*528 + face*8 (chunk stride
// 1056 B; dword stride 264 == 8 mod 32 -> 2-way max bank aliasing for reads
// bank=8*quad+4*l15+wj and rotated writes bank=8*((d+s)&3 rel)+4j+wj).
template <int CIN>
__launch_bounds__(256, 4)
__global__ void conv_mfma_kernel(const unsigned short* __restrict__ x,  // [B][F][CIN] bf16
                                 const int*   __restrict__ gidx,        // [B][F][3]
                                 const unsigned short* __restrict__ wb, // [64][K] bf16
                                 const float* __restrict__ bias,        // [64]
                                 unsigned short* __restrict__ y,        // [B*F][64] bf16
                                 float* __restrict__ pS,                // [nb][64]
                                 float* __restrict__ pQ,                // [nb][64]
                                 int F)
{
    constexpr int K      = 4 * CIN;
    constexpr int NCHUNK = K / 8;            // 16-B chunks of G per face
    constexpr int CPT    = NCHUNK / 4;       // chunks per thread (4 thr/face)
    constexpr int GB     = NCHUNK * 1056;    // G bytes
    constexpr int SB     = (GB > 19456) ? GB : 19456;  // tile(17408)+red(2048)
    __shared__ __align__(16) unsigned char smem[SB];
    unsigned short* Gs  = (unsigned short*)smem;
    float* tile = (float*)smem;                  // [64][68] fp32 (reuses Gs)
    float* redS = (float*)(smem + 17408);        // [4][64]
    float* redQ = redS + 256;                    // [4][64]

    const int b  = blockIdx.y;
    const int f0 = blockIdx.x * 64;
    const int t  = threadIdx.x;

    // ---- phase 1: gather + feature build -> chunk-major LDS ----
    {
        const int j = t >> 2, s = t & 3;         // 4 threads per face
        const int f = f0 + j;
        if (f < F) {
            const unsigned short* xb = x + (size_t)b * F * CIN;
            const int* gp = gidx + ((size_t)b * F + f) * 3;
            const int g0 = gp[0], g1 = gp[1], g2 = gp[2];
            const unsigned short* pc = xb + (size_t)f  * CIN;
            const unsigned short* p0 = xb + (size_t)g0 * CIN;
            const unsigned short* p1 = xb + (size_t)g1 * CIN;
            const unsigned short* p2 = xb + (size_t)g2 * CIN;
#pragma unroll
            for (int i = 0; i < CIN / 32; ++i) {
                const int c0 = s * (CIN / 4) + 8 * i;      // 8 channels
                const ushort8_t vc = *(const ushort8_t*)(pc + c0);
                const ushort8_t v0 = *(const ushort8_t*)(p0 + c0);
                const ushort8_t v1 = *(const ushort8_t*)(p1 + c0);
                const ushort8_t v2 = *(const ushort8_t*)(p2 + c0);
                unsigned short feat[32];
#pragma unroll
                for (int q = 0; q < 8; ++q) {
                    const float ctr = bf2f(vc[q]);
                    const float a   = bf2f(v0[q]);
                    const float bb  = bf2f(v1[q]);
                    const float cc  = bf2f(v2[q]);
                    const float su  = a + bb + cc;
                    const float dd  = fabsf(a - bb) + fabsf(bb - cc) + fabsf(cc - a);
                    const float mm  = fmaxf(a, fmaxf(bb, cc));
                    feat[4 * q + 0] = f2bf(ctr);
                    feat[4 * q + 1] = f2bf(su);
                    feat[4 * q + 2] = f2bf(dd);
                    feat[4 * q + 3] = f2bf(mm);
                }
                const int kc0 = s * CPT + 4 * i;
#pragma unroll
                for (int d = 0; d < 4; ++d) {
                    const int dd_ = (d + s) & 3;           // rotated: 2-way banks
                    *(ushort8_t*)(Gs + (size_t)(kc0 + dd_) * 528 + j * 8) =
                        *(ushort8_t*)(feat + 8 * dd_);
                }
            }
        } else {
            ushort8_t z = {0, 0, 0, 0, 0, 0, 0, 0};
#pragma unroll
            for (int i = 0; i < CIN / 32; ++i) {
                const int kc0 = s * CPT + 4 * i;
#pragma unroll
                for (int d = 0; d < 4; ++d)
                    *(ushort8_t*)(Gs + (size_t)(kc0 + d) * 528 + j * 8) = z;
            }
        }
    }
    __syncthreads();

    // ---- phase 2: MFMA ----
    const int lane = t & 63, wv = t >> 6;
    const int l15 = lane & 15, quad = lane >> 4;

    f32x4 acc[4];
#pragma unroll
    for (int mt = 0; mt < 4; ++mt) acc[mt] = (f32x4){0.f, 0.f, 0.f, 0.f};

    const int n = wv * 16 + l15;
#pragma unroll
    for (int m = 0; m < K / 32; ++m) {
        const int kc = 4 * m + quad;
        const short8 bfr = *(const short8*)(Gs + (size_t)kc * 528 + n * 8);
#pragma unroll
        for (int mt = 0; mt < 4; ++mt) {
            const short8 afr =
                *(const short8*)(wb + (size_t)(mt * 16 + l15) * K + m * 32 + quad * 8);
            acc[mt] = __builtin_amdgcn_mfma_f32_16x16x32_bf16(afr, bfr, acc[mt], 0, 0, 0);
        }
    }
    __syncthreads();   // Gs dead; reuse as tile

    // ---- epilogue: acc -> LDS tile [face][68] (+bias), then stats + bf16 store ----
    {
        const int face = wv * 16 + l15;
#pragma unroll
        for (int mt = 0; mt < 4; ++mt) {
            const int ob = mt * 16 + quad * 4;
            const f32x4 b4 = *(const f32x4*)(bias + ob);
            *(f32x4*)(tile + face * 68 + ob) = acc[mt] + b4;
        }
    }
    __syncthreads();
    {   // pass A: per-block channel partial sums (valid faces only)
        const int o = t & 63, g = t >> 6;
        float S = 0.f, Q = 0.f;
#pragma unroll
        for (int i = 0; i < 16; ++i) {
            const int f = g + 4 * i;
            if (f0 + f < F) {
                const float v = tile[f * 68 + o];
                S += v; Q += v * v;
            }
        }
        redS[g * 64 + o] = S;
        redQ[g * 64 + o] = Q;
    }
    {   // pass B: coalesced bf16 Y store
        const int j = t >> 2, seg = t & 3;
        const int f = f0 + j;
        if (f < F) {
            ushort8_t u0, u1;
#pragma unroll
            for (int ii = 0; ii < 8; ++ii) u0[ii] = f2bf(tile[j * 68 + seg * 16 + ii]);
#pragma unroll
            for (int ii = 0; ii < 8; ++ii) u1[ii] = f2bf(tile[j * 68 + seg * 16 + 8 + ii]);
            unsigned short* yp = y + ((size_t)b * F + f) * 64 + seg * 16;
            *(ushort8_t*)yp       = u0;
            *(ushort8_t*)(yp + 8) = u1;
        }
    }
    __syncthreads();
    if (t < 64) {
        const float S = redS[t] + redS[64 + t] + redS[128 + t] + redS[192 + t];
        const float Q = redQ[t] + redQ[64 + t] + redQ[128 + t] + redQ[192 + t];
        const int blk = blockIdx.y * gridDim.x + blockIdx.x;
        pS[(size_t)blk * 64 + t] = S;
        pQ[(size_t)blk * 64 + t] = Q;
    }
}

// 1 block, 256 threads. Sums nb block-partials; mr[o]=gamma*rsig, mr[64+o]=beta-sc*mu.
__global__ void finalize_kernel(const float* __restrict__ pS, const float* __restrict__ pQ,
                                int nb, float invN,
                                const float* __restrict__ gamma,
                                const float* __restrict__ beta,
                                float* __restrict__ mr)
{
    __shared__ float rs_[256], rq_[256];
    const int t = threadIdx.x, o = t & 63, p = t >> 6;
    float S = 0.f, Q = 0.f;
    for (int j = p; j < nb; j += 4) {
        S += pS[(size_t)j * 64 + o];
        Q += pQ[(size_t)j * 64 + o];
    }
    rs_[t] = S; rq_[t] = Q;
    __syncthreads();
    if (t < 64) {
        S = rs_[t] + rs_[64 + t] + rs_[128 + t] + rs_[192 + t];
        Q = rq_[t] + rq_[64 + t] + rq_[128 + t] + rq_[192 + t];
        const float mu  = S * invN;
        const float var = Q * invN - mu * mu;
        const float rsg = rsqrtf(var + 1e-5f);
        const float sc  = gamma[t] * rsg;
        mr[t]      = sc;
        mr[64 + t] = fmaf(-sc, mu, beta[t]);
    }
}

// BN+res+lrelu, face-major bf16 -> bf16. tid over M*64/4 groups.
__global__ void norm_kernel(const unsigned short* __restrict__ y,   // [M][64] bf16
                            const unsigned short* __restrict__ res, // [M][64] bf16 or null
                            const float* __restrict__ mr,
                            unsigned short* __restrict__ out,       // [M][64] bf16
                            int N4)
{
    const int tid = blockIdx.x * blockDim.x + threadIdx.x;
    if (tid >= N4) return;
    const int c0 = (tid & 15) * 4;
    const ushort4 yv = *(const ushort4*)(y + (size_t)tid * 4);
    const f32x4 sc = *(const f32x4*)(mr + c0);
    const f32x4 sh = *(const f32x4*)(mr + 64 + c0);
    float r[4] = {fmaf(bf2f(yv.x), sc[0], sh[0]), fmaf(bf2f(yv.y), sc[1], sh[1]),
                  fmaf(bf2f(yv.z), sc[2], sh[2]), fmaf(bf2f(yv.w), sc[3], sh[3])};
    if (res) {
        const ushort4 u = *(const ushort4*)(res + (size_t)tid * 4);
        r[0] += bf2f(u.x); r[1] += bf2f(u.y); r[2] += bf2f(u.z); r[3] += bf2f(u.w);
    }
    ushort4 o;
    o.x = f2bf(r[0] >= 0.f ? r[0] : 0.2f * r[0]);
    o.y = f2bf(r[1] >= 0.f ? r[1] : 0.2f * r[1]);
    o.z = f2bf(r[2] >= 0.f ? r[2] : 0.2f * r[2]);
    o.w = f2bf(r[3] >= 0.f ? r[3] : 0.2f * r[3]);
    *(ushort4*)(out + (size_t)tid * 4) = o;
}

// Final BN+res+lrelu fused with transpose [B*F][64] -> [B][64][F] fp32 (d_out).
__global__ void norm_transpose_kernel(const unsigned short* __restrict__ y,   // bf16
                                      const unsigned short* __restrict__ res, // bf16
                                      const float* __restrict__ mr,
                                      float* __restrict__ out, int F)
{
    __shared__ float tile[64 * 65];
    const int b = blockIdx.y, f0 = blockIdx.x * 64, t = threadIdx.x;
    const int j = t >> 2, s = t & 3;
    const int f = f0 + j;
    if (f < F) {
        const size_t row = ((size_t)b * F + f) * 64;
#pragma unroll
        for (int i = 0; i < 4; ++i) {
            const int c0 = (i * 4 + s) * 4;
            const ushort4 yv = *(const ushort4*)(y + row + c0);
            const f32x4 sc = *(const f32x4*)(mr + c0);
            const f32x4 sh = *(const f32x4*)(mr + 64 + c0);
            const ushort4 u = *(const ushort4*)(res + row + c0);
            const float yf[4] = {bf2f(yv.x), bf2f(yv.y), bf2f(yv.z), bf2f(yv.w)};
            const float rv[4] = {bf2f(u.x), bf2f(u.y), bf2f(u.z), bf2f(u.w)};
#pragma unroll
            for (int q = 0; q < 4; ++q) {
                float vv = fmaf(yf[q], sc[q], sh[q]) + rv[q];
                vv = vv >= 0.f ? vv : 0.2f * vv;
                tile[(c0 + q) * 65 + j] = vv;
            }
        }
    }
    __syncthreads();
    const int o = t >> 2;
    float* ob = out + ((size_t)b * 64 + o) * F + f0;
#pragma unroll
    for (int i = 0; i < 4; ++i) {
        const int fs = (i * 4 + s) * 4;
        if (f0 + fs < F) {
            f32x4 v;
#pragma unroll
            for (int q = 0; q < 4; ++q) v[q] = tile[o * 65 + fs + q];
            *(f32x4*)(ob + fs) = v;
        }
    }
}

extern "C" void kernel_launch(void* const* d_in, const int* in_sizes, int n_in,
                              void* d_out, int out_size, void* d_ws, size_t ws_size,
                              hipStream_t stream)
{
    const float* fe  = (const float*)d_in[0];
    const int*   gm  = (const int*)d_in[1];
    const float* w1  = (const float*)d_in[2];
    const float* b1  = (const float*)d_in[3];
    const float* w2a = (const float*)d_in[4];
    const float* b2a = (const float*)d_in[5];
    const float* w2b = (const float*)d_in[6];
    const float* b2b = (const float*)d_in[7];
    const float* g0  = (const float*)d_in[8];
    const float* be0 = (const float*)d_in[9];
    const float* g1  = (const float*)d_in[10];
    const float* be1 = (const float*)d_in[11];
    const float* g2  = (const float*)d_in[12];
    const float* be2 = (const float*)d_in[13];

    const int B = 4, O = 64;
    const int F = in_sizes[0] / (B * 32);
    const int M = B * F;
    const float invN = 1.0f / (float)M;
    const int nbx = (F + 63) / 64;
    const int nb  = nbx * B;

    // Workspace: bufY bf16 [M][64] + xbuf bf16 [M][64] + partials + weights.
    unsigned short* bufY = (unsigned short*)d_ws;
    unsigned short* xbuf = bufY + (size_t)M * O;
    float* pS   = (float*)(xbuf + (size_t)M * O);       // [nb][64]
    float* pQ   = pS + (size_t)nb * 64;                 // [nb][64]
    float* mr   = pQ + (size_t)nb * 64;                 // [2][64]
    unsigned short* w1b  = (unsigned short*)(mr + 128); // [64][128]
    unsigned short* w2ab = w1b + 64 * 128;              // [64][256]
    unsigned short* w2bb = w2ab + 64 * 256;             // [64][256]
    unsigned short* fe_t = (unsigned short*)d_out;      // [B][F][32] bf16, dead after conv1

    dim3 blk(256);
    dim3 cgrid(nbx, B);
    const int N4 = M * 16;
    dim3 ngrid((N4 + 255) / 256);

    transpose_fe_kernel<<<cgrid, blk, 0, stream>>>(fe, fe_t, F);
    cast_weights_kernel<<<64, 256, 0, stream>>>(w1, w2a, w2b, w1b, w2ab, w2bb);

    // ---- Stage 1 ----
    conv_mfma_kernel<32><<<cgrid, blk, 0, stream>>>(fe_t, gm, w1b, b1, bufY, pS, pQ, F);
    finalize_kernel<<<1, 256, 0, stream>>>(pS, pQ, nb, invN, g0, be0, mr);
    norm_kernel<<<ngrid, blk, 0, stream>>>(bufY, nullptr, mr, xbuf, N4);

    // ---- Stage 2 ----
    conv_mfma_kernel<64><<<cgrid, blk, 0, stream>>>(xbuf, gm, w2ab, b2a, bufY, pS, pQ, F);
    finalize_kernel<<<1, 256, 0, stream>>>(pS, pQ, nb, invN, g1, be1, mr);
    norm_kernel<<<ngrid, blk, 0, stream>>>(bufY, xbuf, mr, xbuf, N4);

    // ---- Stage 3 ----
    conv_mfma_kernel<64><<<cgrid, blk, 0, stream>>>(xbuf, gm, w2bb, b2b, bufY, pS, pQ, F);
    finalize_kernel<<<1, 256, 0, stream>>>(pS, pQ, nb, invN, g2, be2, mr);
    norm_transpose_kernel<<<cgrid, blk, 0, stream>>>(bufY, xbuf, mr, (float*)d_out, F);
}

// Round 5
// 579.378 us; speedup vs baseline: 2.0343x; 2.0343x over previous
//
#include <hip/hip_runtime.h>
#include <math.h>

// DownConvFace: 3 stages of {mesh_conv -> BN(global stats) -> (+res) -> LeakyReLU(0.2)}
// B=4, F=50000, Cin=32/64/64, O=64, fp32 in/out.
//
// R5: fix R4's serial finalize (209us: 1 block x 782 dependent-load iterations).
// Partials now [64][nb] (channel-major, coalesced) and finalize is 64 blocks
// (one per channel) x 256 threads with LDS tree reduce.

typedef __attribute__((ext_vector_type(8))) short short8;
typedef __attribute__((ext_vector_type(8))) unsigned short ushort8_t;
typedef __attribute__((ext_vector_type(4))) float f32x4;

__device__ inline unsigned short f2bf(float v) {
    union { float f; unsigned u; } x; x.f = v;
    unsigned r = x.u + 0x7fffu + ((x.u >> 16) & 1u);   // RNE
    return (unsigned short)(r >> 16);
}
__device__ inline float bf2f(unsigned short u) {
    union { unsigned u; float f; } x; x.u = ((unsigned)u) << 16; return x.f;
}

// fe [B][32][F] fp32 -> fe_t [B][F][32] bf16. grid (ceil(F/64), B), block 256.
__global__ void transpose_fe_kernel(const float* __restrict__ fe,
                                    unsigned short* __restrict__ o, int F)
{
    __shared__ float tile[64 * 33];
    const int b = blockIdx.y;
    const int f0 = blockIdx.x * 64;
    const int t = threadIdx.x;
    const int lane = t & 63;
    const int w = t >> 6;
    const int f = f0 + lane;
    if (f < F) {
#pragma unroll
        for (int i = 0; i < 8; ++i) {
            const int c = w * 8 + i;
            tile[lane * 33 + c] = fe[((size_t)b * 32 + c) * F + f];
        }
    }
    __syncthreads();
    const int j = t >> 2, s = t & 3;
    const int fj = f0 + j;
    if (fj < F) {
        ushort8_t v;
#pragma unroll
        for (int i = 0; i < 8; ++i) v[i] = f2bf(tile[j * 33 + s * 8 + i]);
        *(ushort8_t*)(o + ((size_t)b * F + fj) * 32 + s * 8) = v;
    }
}

// Cast weights fp32->bf16 (flat; [O][C][4] == [O][4C], k=4c+kk).
__global__ void cast_weights_kernel(const float* __restrict__ w1,
                                    const float* __restrict__ w2a,
                                    const float* __restrict__ w2b,
                                    unsigned short* __restrict__ w1b,
                                    unsigned short* __restrict__ w2ab,
                                    unsigned short* __restrict__ w2bb)
{
    const int i = blockIdx.x * blockDim.x + threadIdx.x;
    if (i < 64 * 128) w1b[i] = f2bf(w1[i]);
    if (i < 64 * 256) { w2ab[i] = f2bf(w2a[i]); w2bb[i] = f2bf(w2b[i]); }
}

// Fused mesh-conv GEMM + BN-stats epilogue. Block 256 (4 waves), 64 faces x 64 o.
// grid = (ceil(F/64), B). Y out bf16 [B*F][64]; per-block stats to pS/pQ [64][nb].
template <int CIN>
__launch_bounds__(256, 4)
__global__ void conv_mfma_kernel(const unsigned short* __restrict__ x,  // [B][F][CIN] bf16
                                 const int*   __restrict__ gidx,        // [B][F][3]
                                 const unsigned short* __restrict__ wb, // [64][K] bf16
                                 const float* __restrict__ bias,        // [64]
                                 unsigned short* __restrict__ y,        // [B*F][64] bf16
                                 float* __restrict__ pS,                // [64][nb]
                                 float* __restrict__ pQ,                // [64][nb]
                                 int nb, int F)
{
    constexpr int K      = 4 * CIN;
    constexpr int NCHUNK = K / 8;            // 16-B chunks of G per face
    constexpr int CPT    = NCHUNK / 4;       // chunks per thread (4 thr/face)
    constexpr int GB     = NCHUNK * 1056;    // G bytes
    constexpr int SB     = (GB > 19456) ? GB : 19456;  // tile(17408)+red(2048)
    __shared__ __align__(16) unsigned char smem[SB];
    unsigned short* Gs  = (unsigned short*)smem;
    float* tile = (float*)smem;                  // [64][68] fp32 (reuses Gs)
    float* redS = (float*)(smem + 17408);        // [4][64]
    float* redQ = redS + 256;                    // [4][64]

    const int b  = blockIdx.y;
    const int f0 = blockIdx.x * 64;
    const int t  = threadIdx.x;

    // ---- phase 1: gather + feature build -> chunk-major LDS ----
    {
        const int j = t >> 2, s = t & 3;         // 4 threads per face
        const int f = f0 + j;
        if (f < F) {
            const unsigned short* xb = x + (size_t)b * F * CIN;
            const int* gp = gidx + ((size_t)b * F + f) * 3;
            const int g0 = gp[0], g1 = gp[1], g2 = gp[2];
            const unsigned short* pc = xb + (size_t)f  * CIN;
            const unsigned short* p0 = xb + (size_t)g0 * CIN;
            const unsigned short* p1 = xb + (size_t)g1 * CIN;
            const unsigned short* p2 = xb + (size_t)g2 * CIN;
#pragma unroll
            for (int i = 0; i < CIN / 32; ++i) {
                const int c0 = s * (CIN / 4) + 8 * i;      // 8 channels
                const ushort8_t vc = *(const ushort8_t*)(pc + c0);
                const ushort8_t v0 = *(const ushort8_t*)(p0 + c0);
                const ushort8_t v1 = *(const ushort8_t*)(p1 + c0);
                const ushort8_t v2 = *(const ushort8_t*)(p2 + c0);
                unsigned short feat[32];
#pragma unroll
                for (int q = 0; q < 8; ++q) {
                    const float ctr = bf2f(vc[q]);
                    const float a   = bf2f(v0[q]);
                    const float bb  = bf2f(v1[q]);
                    const float cc  = bf2f(v2[q]);
                    const float su  = a + bb + cc;
                    const float dd  = fabsf(a - bb) + fabsf(bb - cc) + fabsf(cc - a);
                    const float mm  = fmaxf(a, fmaxf(bb, cc));
                    feat[4 * q + 0] = f2bf(ctr);
                    feat[4 * q + 1] = f2bf(su);
                    feat[4 * q + 2] = f2bf(dd);
                    feat[4 * q + 3] = f2bf(mm);
                }
                const int kc0 = s * CPT + 4 * i;
#pragma unroll
                for (int d = 0; d < 4; ++d) {
                    const int dd_ = (d + s) & 3;           // rotated: 2-way banks
                    *(ushort8_t*)(Gs + (size_t)(kc0 + dd_) * 528 + j * 8) =
                        *(ushort8_t*)(feat + 8 * dd_);
                }
            }
        } else {
            ushort8_t z = {0, 0, 0, 0, 0, 0, 0, 0};
#pragma unroll
            for (int i = 0; i < CIN / 32; ++i) {
                const int kc0 = s * CPT + 4 * i;
#pragma unroll
                for (int d = 0; d < 4; ++d)
                    *(ushort8_t*)(Gs + (size_t)(kc0 + d) * 528 + j * 8) = z;
            }
        }
    }
    __syncthreads();

    // ---- phase 2: MFMA ----
    const int lane = t & 63, wv = t >> 6;
    const int l15 = lane & 15, quad = lane >> 4;

    f32x4 acc[4];
#pragma unroll
    for (int mt = 0; mt < 4; ++mt) acc[mt] = (f32x4){0.f, 0.f, 0.f, 0.f};

    const int n = wv * 16 + l15;
#pragma unroll
    for (int m = 0; m < K / 32; ++m) {
        const int kc = 4 * m + quad;
        const short8 bfr = *(const short8*)(Gs + (size_t)kc * 528 + n * 8);
#pragma unroll
        for (int mt = 0; mt < 4; ++mt) {
            const short8 afr =
                *(const short8*)(wb + (size_t)(mt * 16 + l15) * K + m * 32 + quad * 8);
            acc[mt] = __builtin_amdgcn_mfma_f32_16x16x32_bf16(afr, bfr, acc[mt], 0, 0, 0);
        }
    }
    __syncthreads();   // Gs dead; reuse as tile

    // ---- epilogue: acc -> LDS tile [face][68] (+bias), then stats + bf16 store ----
    {
        const int face = wv * 16 + l15;
#pragma unroll
        for (int mt = 0; mt < 4; ++mt) {
            const int ob = mt * 16 + quad * 4;
            const f32x4 b4 = *(const f32x4*)(bias + ob);
            *(f32x4*)(tile + face * 68 + ob) = acc[mt] + b4;
        }
    }
    __syncthreads();
    {   // pass A: per-block channel partial sums (valid faces only)
        const int o = t & 63, g = t >> 6;
        float S = 0.f, Q = 0.f;
#pragma unroll
        for (int i = 0; i < 16; ++i) {
            const int f = g + 4 * i;
            if (f0 + f < F) {
                const float v = tile[f * 68 + o];
                S += v; Q += v * v;
            }
        }
        redS[g * 64 + o] = S;
        redQ[g * 64 + o] = Q;
    }
    {   // pass B: coalesced bf16 Y store
        const int j = t >> 2, seg = t & 3;
        const int f = f0 + j;
        if (f < F) {
            ushort8_t u0, u1;
#pragma unroll
            for (int ii = 0; ii < 8; ++ii) u0[ii] = f2bf(tile[j * 68 + seg * 16 + ii]);
#pragma unroll
            for (int ii = 0; ii < 8; ++ii) u1[ii] = f2bf(tile[j * 68 + seg * 16 + 8 + ii]);
            unsigned short* yp = y + ((size_t)b * F + f) * 64 + seg * 16;
            *(ushort8_t*)yp       = u0;
            *(ushort8_t*)(yp + 8) = u1;
        }
    }
    __syncthreads();
    if (t < 64) {
        const float S = redS[t] + redS[64 + t] + redS[128 + t] + redS[192 + t];
        const float Q = redQ[t] + redQ[64 + t] + redQ[128 + t] + redQ[192 + t];
        const int blk = blockIdx.y * gridDim.x + blockIdx.x;
        pS[(size_t)t * nb + blk] = S;     // channel-major: coalesced finalize reads
        pQ[(size_t)t * nb + blk] = Q;
    }
}

// grid 64 (one block per channel), 256 threads. Contiguous reads of pS/pQ[o][0..nb).
__global__ void finalize_kernel(const float* __restrict__ pS, const float* __restrict__ pQ,
                                int nb, float invN,
                                const float* __restrict__ gamma,
                                const float* __restrict__ beta,
                                float* __restrict__ mr)
{
    __shared__ float rs_[256], rq_[256];
    const int o = blockIdx.x, t = threadIdx.x;
    float S = 0.f, Q = 0.f;
    for (int j = t; j < nb; j += 256) {
        S += pS[(size_t)o * nb + j];
        Q += pQ[(size_t)o * nb + j];
    }
    rs_[t] = S; rq_[t] = Q;
    __syncthreads();
#pragma unroll
    for (int s = 128; s > 0; s >>= 1) {
        if (t < s) { rs_[t] += rs_[t + s]; rq_[t] += rq_[t + s]; }
        __syncthreads();
    }
    if (t == 0) {
        const float mu  = rs_[0] * invN;
        const float var = rq_[0] * invN - mu * mu;
        const float rsg = rsqrtf(var + 1e-5f);
        const float sc  = gamma[o] * rsg;
        mr[o]      = sc;
        mr[64 + o] = fmaf(-sc, mu, beta[o]);
    }
}

// BN+res+lrelu, face-major bf16 -> bf16. tid over M*64/4 groups.
__global__ void norm_kernel(const unsigned short* __restrict__ y,   // [M][64] bf16
                            const unsigned short* __restrict__ res, // [M][64] bf16 or null
                            const float* __restrict__ mr,
                            unsigned short* __restrict__ out,       // [M][64] bf16
                            int N4)
{
    const int tid = blockIdx.x * blockDim.x + threadIdx.x;
    if (tid >= N4) return;
    const int c0 = (tid & 15) * 4;
    const ushort4 yv = *(const ushort4*)(y + (size_t)tid * 4);
    const f32x4 sc = *(const f32x4*)(mr + c0);
    const f32x4 sh = *(const f32x4*)(mr + 64 + c0);
    float r[4] = {fmaf(bf2f(yv.x), sc[0], sh[0]), fmaf(bf2f(yv.y), sc[1], sh[1]),
                  fmaf(bf2f(yv.z), sc[2], sh[2]), fmaf(bf2f(yv.w), sc[3], sh[3])};
    if (res) {
        const ushort4 u = *(const ushort4*)(res + (size_t)tid * 4);
        r[0] += bf2f(u.x); r[1] += bf2f(u.y); r[2] += bf2f(u.z); r[3] += bf2f(u.w);
    }
    ushort4 o;
    o.x = f2bf(r[0] >= 0.f ? r[0] : 0.2f * r[0]);
    o.y = f2bf(r[1] >= 0.f ? r[1] : 0.2f * r[1]);
    o.z = f2bf(r[2] >= 0.f ? r[2] : 0.2f * r[2]);
    o.w = f2bf(r[3] >= 0.f ? r[3] : 0.2f * r[3]);
    *(ushort4*)(out + (size_t)tid * 4) = o;
}

// Final BN+res+lrelu fused with transpose [B*F][64] -> [B][64][F] fp32 (d_out).
__global__ void norm_transpose_kernel(const unsigned short* __restrict__ y,   // bf16
                                      const unsigned short* __restrict__ res, // bf16
                                      const float* __restrict__ mr,
                                      float* __restrict__ out, int F)
{
    __shared__ float tile[64 * 65];
    const int b = blockIdx.y, f0 = blockIdx.x * 64, t = threadIdx.x;
    const int j = t >> 2, s = t & 3;
    const int f = f0 + j;
    if (f < F) {
        const size_t row = ((size_t)b * F + f) * 64;
#pragma unroll
        for (int i = 0; i < 4; ++i) {
            const int c0 = (i * 4 + s) * 4;
            const ushort4 yv = *(const ushort4*)(y + row + c0);
            const f32x4 sc = *(const f32x4*)(mr + c0);
            const f32x4 sh = *(const f32x4*)(mr + 64 + c0);
            const ushort4 u = *(const ushort4*)(res + row + c0);
            const float yf[4] = {bf2f(yv.x), bf2f(yv.y), bf2f(yv.z), bf2f(yv.w)};
            const float rv[4] = {bf2f(u.x), bf2f(u.y), bf2f(u.z), bf2f(u.w)};
#pragma unroll
            for (int q = 0; q < 4; ++q) {
                float vv = fmaf(yf[q], sc[q], sh[q]) + rv[q];
                vv = vv >= 0.f ? vv : 0.2f * vv;
                tile[(c0 + q) * 65 + j] = vv;
            }
        }
    }
    __syncthreads();
    const int o = t >> 2;
    float* ob = out + ((size_t)b * 64 + o) * F + f0;
#pragma unroll
    for (int i = 0; i < 4; ++i) {
        const int fs = (i * 4 + s) * 4;
        if (f0 + fs < F) {
            f32x4 v;
#pragma unroll
            for (int q = 0; q < 4; ++q) v[q] = tile[o * 65 + fs + q];
            *(f32x4*)(ob + fs) = v;
        }
    }
}

extern "C" void kernel_launch(void* const* d_in, const int* in_sizes, int n_in,
                              void* d_out, int out_size, void* d_ws, size_t ws_size,
                              hipStream_t stream)
{
    const float* fe  = (const float*)d_in[0];
    const int*   gm  = (const int*)d_in[1];
    const float* w1  = (const float*)d_in[2];
    const float* b1  = (const float*)d_in[3];
    const float* w2a = (const float*)d_in[4];
    const float* b2a = (const float*)d_in[5];
    const float* w2b = (const float*)d_in[6];
    const float* b2b = (const float*)d_in[7];
    const float* g0  = (const float*)d_in[8];
    const float* be0 = (const float*)d_in[9];
    const float* g1  = (const float*)d_in[10];
    const float* be1 = (const float*)d_in[11];
    const float* g2  = (const float*)d_in[12];
    const float* be2 = (const float*)d_in[13];

    const int B = 4, O = 64;
    const int F = in_sizes[0] / (B * 32);
    const int M = B * F;
    const float invN = 1.0f / (float)M;
    const int nbx = (F + 63) / 64;
    const int nb  = nbx * B;

    // Workspace: bufY bf16 [M][64] + xbuf bf16 [M][64] + partials + weights.
    unsigned short* bufY = (unsigned short*)d_ws;
    unsigned short* xbuf = bufY + (size_t)M * O;
    float* pS   = (float*)(xbuf + (size_t)M * O);       // [64][nb]
    float* pQ   = pS + (size_t)64 * nb;                 // [64][nb]
    float* mr   = pQ + (size_t)64 * nb;                 // [2][64]
    unsigned short* w1b  = (unsigned short*)(mr + 128); // [64][128]
    unsigned short* w2ab = w1b + 64 * 128;              // [64][256]
    unsigned short* w2bb = w2ab + 64 * 256;             // [64][256]
    unsigned short* fe_t = (unsigned short*)d_out;      // [B][F][32] bf16, dead after conv1

    dim3 blk(256);
    dim3 cgrid(nbx, B);
    const int N4 = M * 16;
    dim3 ngrid((N4 + 255) / 256);

    transpose_fe_kernel<<<cgrid, blk, 0, stream>>>(fe, fe_t, F);
    cast_weights_kernel<<<64, 256, 0, stream>>>(w1, w2a, w2b, w1b, w2ab, w2bb);

    // ---- Stage 1 ----
    conv_mfma_kernel<32><<<cgrid, blk, 0, stream>>>(fe_t, gm, w1b, b1, bufY, pS, pQ, nb, F);
    finalize_kernel<<<64, 256, 0, stream>>>(pS, pQ, nb, invN, g0, be0, mr);
    norm_kernel<<<ngrid, blk, 0, stream>>>(bufY, nullptr, mr, xbuf, N4);

    // ---- Stage 2 ----
    conv_mfma_kernel<64><<<cgrid, blk, 0, stream>>>(xbuf, gm, w2ab, b2a, bufY, pS, pQ, nb, F);
    finalize_kernel<<<64, 256, 0, stream>>>(pS, pQ, nb, invN, g1, be1, mr);
    norm_kernel<<<ngrid, blk, 0, stream>>>(bufY, xbuf, mr, xbuf, N4);

    // ---- Stage 3 ----
    conv_mfma_kernel<64><<<cgrid, blk, 0, stream>>>(xbuf, gm, w2bb, b2b, bufY, pS, pQ, nb, F);
    finalize_kernel<<<64, 256, 0, stream>>>(pS, pQ, nb, invN, g2, be2, mr);
    norm_transpose_kernel<<<cgrid, blk, 0, stream>>>(bufY, xbuf, mr, (float*)d_out, F);
}

// Round 6
// 327.416 us; speedup vs baseline: 3.5998x; 1.7695x over previous
//
#include <hip/hip_runtime.h>
#include <math.h>

// DownConvFace: 3 stages of {mesh_conv -> BN(global stats) -> (+res) -> LeakyReLU(0.2)}
// B=4, F=50000, Cin=32/64/64, O=64, fp32 in/out.
//
// R6: revert R4's chunk-major+rotated LDS (dynamic index into local array ->
// scratch spill: +100MB HBM traffic, VALUBusy 81%) back to R3's face-major
// static-index layout (proven 68us). Keep: fused BN-stats conv epilogue,
// bf16 Y, channel-major partials + parallel finalize, bf16 norm kernels.

typedef __attribute__((ext_vector_type(8))) short short8;
typedef __attribute__((ext_vector_type(8))) unsigned short ushort8_t;
typedef __attribute__((ext_vector_type(4))) float f32x4;

__device__ inline unsigned short f2bf(float v) {
    union { float f; unsigned u; } x; x.f = v;
    unsigned r = x.u + 0x7fffu + ((x.u >> 16) & 1u);   // RNE
    return (unsigned short)(r >> 16);
}
__device__ inline float bf2f(unsigned short u) {
    union { unsigned u; float f; } x; x.u = ((unsigned)u) << 16; return x.f;
}

// fe [B][32][F] fp32 -> fe_t [B][F][32] bf16. grid (ceil(F/64), B), block 256.
__global__ void transpose_fe_kernel(const float* __restrict__ fe,
                                    unsigned short* __restrict__ o, int F)
{
    __shared__ float tile[64 * 33];
    const int b = blockIdx.y;
    const int f0 = blockIdx.x * 64;
    const int t = threadIdx.x;
    const int lane = t & 63;
    const int w = t >> 6;
    const int f = f0 + lane;
    if (f < F) {
#pragma unroll
        for (int i = 0; i < 8; ++i) {
            const int c = w * 8 + i;
            tile[lane * 33 + c] = fe[((size_t)b * 32 + c) * F + f];
        }
    }
    __syncthreads();
    const int j = t >> 2, s = t & 3;
    const int fj = f0 + j;
    if (fj < F) {
        ushort8_t v;
#pragma unroll
        for (int i = 0; i < 8; ++i) v[i] = f2bf(tile[j * 33 + s * 8 + i]);
        *(ushort8_t*)(o + ((size_t)b * F + fj) * 32 + s * 8) = v;
    }
}

// Cast weights fp32->bf16 (flat; [O][C][4] == [O][4C], k=4c+kk).
__global__ void cast_weights_kernel(const float* __restrict__ w1,
                                    const float* __restrict__ w2a,
                                    const float* __restrict__ w2b,
                                    unsigned short* __restrict__ w1b,
                                    unsigned short* __restrict__ w2ab,
                                    unsigned short* __restrict__ w2bb)
{
    const int i = blockIdx.x * blockDim.x + threadIdx.x;
    if (i < 64 * 128) w1b[i] = f2bf(w1[i]);
    if (i < 64 * 256) { w2ab[i] = f2bf(w2a[i]); w2bb[i] = f2bf(w2b[i]); }
}

// Fused mesh-conv GEMM + BN-stats epilogue. Block 256 (4 waves), 64 faces x 64 o.
// grid = (ceil(F/64), B). Y out bf16 [B*F][64]; per-block stats to pS/pQ [64][nb].
// G LDS: face-major rows, LDK = K+8 shorts (static indexing only — R4's rotated
// dynamic index spilled the feat array to scratch: +100MB HBM, 17x VALU).
template <int CIN>
__launch_bounds__(256, 4)
__global__ void conv_mfma_kernel(const unsigned short* __restrict__ x,  // [B][F][CIN] bf16
                                 const int*   __restrict__ gidx,        // [B][F][3]
                                 const unsigned short* __restrict__ wb, // [64][K] bf16
                                 const float* __restrict__ bias,        // [64]
                                 unsigned short* __restrict__ y,        // [B*F][64] bf16
                                 float* __restrict__ pS,                // [64][nb]
                                 float* __restrict__ pQ,                // [64][nb]
                                 int nb, int F)
{
    constexpr int K   = 4 * CIN;
    constexpr int LDK = K + 8;
    constexpr int GB  = 64 * LDK * 2;                  // G bytes
    constexpr int SB  = (GB > 19456) ? GB : 19456;     // tile(17408)+red(2048)
    __shared__ __align__(16) unsigned char smem[SB];
    unsigned short* Gs = (unsigned short*)smem;
    float* tile = (float*)smem;                  // [64][68] fp32 (reuses Gs)
    float* redS = (float*)(smem + 17408);        // [4][64]
    float* redQ = redS + 256;                    // [4][64]

    const int b  = blockIdx.y;
    const int f0 = blockIdx.x * 64;
    const int t  = threadIdx.x;

    // ---- phase 1: gather contiguous bf16 rows, build features into LDS ----
    {
        const int j = t >> 2, s = t & 3;         // 4 threads per face
        const int f = f0 + j;
        unsigned short* gr = &Gs[j * LDK];
        if (f < F) {
            const unsigned short* xb = x + (size_t)b * F * CIN;
            const int* gp = gidx + ((size_t)b * F + f) * 3;
            const int g0 = gp[0], g1 = gp[1], g2 = gp[2];
            const unsigned short* pc = xb + (size_t)f  * CIN;
            const unsigned short* p0 = xb + (size_t)g0 * CIN;
            const unsigned short* p1 = xb + (size_t)g1 * CIN;
            const unsigned short* p2 = xb + (size_t)g2 * CIN;
#pragma unroll
            for (int i = 0; i < CIN / 32; ++i) {
                const int c0 = (i * 4 + s) * 8;          // 8 channels, 16B loads
                const ushort8_t vc = *(const ushort8_t*)(pc + c0);
                const ushort8_t v0 = *(const ushort8_t*)(p0 + c0);
                const ushort8_t v1 = *(const ushort8_t*)(p1 + c0);
                const ushort8_t v2 = *(const ushort8_t*)(p2 + c0);
                unsigned short feat[32];
#pragma unroll
                for (int q = 0; q < 8; ++q) {
                    const float ctr = bf2f(vc[q]);
                    const float a   = bf2f(v0[q]);
                    const float bb  = bf2f(v1[q]);
                    const float cc  = bf2f(v2[q]);
                    const float su  = a + bb + cc;
                    const float dd  = fabsf(a - bb) + fabsf(bb - cc) + fabsf(cc - a);
                    const float mm  = fmaxf(a, fmaxf(bb, cc));
                    feat[4 * q + 0] = f2bf(ctr);
                    feat[4 * q + 1] = f2bf(su);
                    feat[4 * q + 2] = f2bf(dd);
                    feat[4 * q + 3] = f2bf(mm);
                }
#pragma unroll
                for (int q4 = 0; q4 < 4; ++q4)          // static indices only
                    *(ushort8_t*)(gr + 4 * c0 + q4 * 8) = *(ushort8_t*)(feat + q4 * 8);
            }
        } else {
            ushort8_t z = {0, 0, 0, 0, 0, 0, 0, 0};
#pragma unroll
            for (int i = 0; i < CIN / 32; ++i) {
                const int c0 = (i * 4 + s) * 8;
#pragma unroll
                for (int q4 = 0; q4 < 4; ++q4)
                    *(ushort8_t*)(gr + 4 * c0 + q4 * 8) = z;
            }
        }
    }
    __syncthreads();

    // ---- phase 2: MFMA ----
    const int lane = t & 63, wv = t >> 6;
    const int l15 = lane & 15, quad = lane >> 4;
    const int kb = quad * 8;

    f32x4 acc[4];
#pragma unroll
    for (int mt = 0; mt < 4; ++mt) acc[mt] = (f32x4){0.f, 0.f, 0.f, 0.f};

    const int n = wv * 16 + l15;
#pragma unroll
    for (int ks = 0; ks < K; ks += 32) {
        const short8 bfr = *(const short8*)&Gs[n * LDK + ks + kb];
#pragma unroll
        for (int mt = 0; mt < 4; ++mt) {
            const short8 afr = *(const short8*)(wb + (size_t)(mt * 16 + l15) * K + ks + kb);
            acc[mt] = __builtin_amdgcn_mfma_f32_16x16x32_bf16(afr, bfr, acc[mt], 0, 0, 0);
        }
    }
    __syncthreads();   // Gs dead; reuse as tile

    // ---- epilogue: acc -> LDS tile [face][68] (+bias), then stats + bf16 store ----
    {
        const int face = wv * 16 + l15;
#pragma unroll
        for (int mt = 0; mt < 4; ++mt) {
            const int ob = mt * 16 + quad * 4;
            const f32x4 b4 = *(const f32x4*)(bias + ob);
            *(f32x4*)(tile + face * 68 + ob) = acc[mt] + b4;
        }
    }
    __syncthreads();
    {   // pass A: per-block channel partial sums (valid faces only)
        const int o = t & 63, g = t >> 6;
        float S = 0.f, Q = 0.f;
#pragma unroll
        for (int i = 0; i < 16; ++i) {
            const int f = g + 4 * i;
            if (f0 + f < F) {
                const float v = tile[f * 68 + o];
                S += v; Q += v * v;
            }
        }
        redS[g * 64 + o] = S;
        redQ[g * 64 + o] = Q;
    }
    {   // pass B: coalesced bf16 Y store
        const int j = t >> 2, seg = t & 3;
        const int f = f0 + j;
        if (f < F) {
            ushort8_t u0, u1;
#pragma unroll
            for (int ii = 0; ii < 8; ++ii) u0[ii] = f2bf(tile[j * 68 + seg * 16 + ii]);
#pragma unroll
            for (int ii = 0; ii < 8; ++ii) u1[ii] = f2bf(tile[j * 68 + seg * 16 + 8 + ii]);
            unsigned short* yp = y + ((size_t)b * F + f) * 64 + seg * 16;
            *(ushort8_t*)yp       = u0;
            *(ushort8_t*)(yp + 8) = u1;
        }
    }
    __syncthreads();
    if (t < 64) {
        const float S = redS[t] + redS[64 + t] + redS[128 + t] + redS[192 + t];
        const float Q = redQ[t] + redQ[64 + t] + redQ[128 + t] + redQ[192 + t];
        const int blk = blockIdx.y * gridDim.x + blockIdx.x;
        pS[(size_t)t * nb + blk] = S;     // channel-major: coalesced finalize reads
        pQ[(size_t)t * nb + blk] = Q;
    }
}

// grid 64 (one block per channel), 256 threads. Contiguous reads of pS/pQ[o][0..nb).
__global__ void finalize_kernel(const float* __restrict__ pS, const float* __restrict__ pQ,
                                int nb, float invN,
                                const float* __restrict__ gamma,
                                const float* __restrict__ beta,
                                float* __restrict__ mr)
{
    __shared__ float rs_[256], rq_[256];
    const int o = blockIdx.x, t = threadIdx.x;
    float S = 0.f, Q = 0.f;
    for (int j = t; j < nb; j += 256) {
        S += pS[(size_t)o * nb + j];
        Q += pQ[(size_t)o * nb + j];
    }
    rs_[t] = S; rq_[t] = Q;
    __syncthreads();
#pragma unroll
    for (int s = 128; s > 0; s >>= 1) {
        if (t < s) { rs_[t] += rs_[t + s]; rq_[t] += rq_[t + s]; }
        __syncthreads();
    }
    if (t == 0) {
        const float mu  = rs_[0] * invN;
        const float var = rq_[0] * invN - mu * mu;
        const float rsg = rsqrtf(var + 1e-5f);
        const float sc  = gamma[o] * rsg;
        mr[o]      = sc;
        mr[64 + o] = fmaf(-sc, mu, beta[o]);
    }
}

// BN+res+lrelu, face-major bf16 -> bf16. tid over M*64/4 groups.
__global__ void norm_kernel(const unsigned short* __restrict__ y,   // [M][64] bf16
                            const unsigned short* __restrict__ res, // [M][64] bf16 or null
                            const float* __restrict__ mr,
                            unsigned short* __restrict__ out,       // [M][64] bf16
                            int N4)
{
    const int tid = blockIdx.x * blockDim.x + threadIdx.x;
    if (tid >= N4) return;
    const int c0 = (tid & 15) * 4;
    const ushort4 yv = *(const ushort4*)(y + (size_t)tid * 4);
    const f32x4 sc = *(const f32x4*)(mr + c0);
    const f32x4 sh = *(const f32x4*)(mr + 64 + c0);
    float r[4] = {fmaf(bf2f(yv.x), sc[0], sh[0]), fmaf(bf2f(yv.y), sc[1], sh[1]),
                  fmaf(bf2f(yv.z), sc[2], sh[2]), fmaf(bf2f(yv.w), sc[3], sh[3])};
    if (res) {
        const ushort4 u = *(const ushort4*)(res + (size_t)tid * 4);
        r[0] += bf2f(u.x); r[1] += bf2f(u.y); r[2] += bf2f(u.z); r[3] += bf2f(u.w);
    }
    ushort4 o;
    o.x = f2bf(r[0] >= 0.f ? r[0] : 0.2f * r[0]);
    o.y = f2bf(r[1] >= 0.f ? r[1] : 0.2f * r[1]);
    o.z = f2bf(r[2] >= 0.f ? r[2] : 0.2f * r[2]);
    o.w = f2bf(r[3] >= 0.f ? r[3] : 0.2f * r[3]);
    *(ushort4*)(out + (size_t)tid * 4) = o;
}

// Final BN+res+lrelu fused with transpose [B*F][64] -> [B][64][F] fp32 (d_out).
__global__ void norm_transpose_kernel(const unsigned short* __restrict__ y,   // bf16
                                      const unsigned short* __restrict__ res, // bf16
                                      const float* __restrict__ mr,
                                      float* __restrict__ out, int F)
{
    __shared__ float tile[64 * 65];
    const int b = blockIdx.y, f0 = blockIdx.x * 64, t = threadIdx.x;
    const int j = t >> 2, s = t & 3;
    const int f = f0 + j;
    if (f < F) {
        const size_t row = ((size_t)b * F + f) * 64;
#pragma unroll
        for (int i = 0; i < 4; ++i) {
            const int c0 = (i * 4 + s) * 4;
            const ushort4 yv = *(const ushort4*)(y + row + c0);
            const f32x4 sc = *(const f32x4*)(mr + c0);
            const f32x4 sh = *(const f32x4*)(mr + 64 + c0);
            const ushort4 u = *(const ushort4*)(res + row + c0);
            const float yf[4] = {bf2f(yv.x), bf2f(yv.y), bf2f(yv.z), bf2f(yv.w)};
            const float rv[4] = {bf2f(u.x), bf2f(u.y), bf2f(u.z), bf2f(u.w)};
#pragma unroll
            for (int q = 0; q < 4; ++q) {
                float vv = fmaf(yf[q], sc[q], sh[q]) + rv[q];
                vv = vv >= 0.f ? vv : 0.2f * vv;
                tile[(c0 + q) * 65 + j] = vv;
            }
        }
    }
    __syncthreads();
    const int o = t >> 2;
    float* ob = out + ((size_t)b * 64 + o) * F + f0;
#pragma unroll
    for (int i = 0; i < 4; ++i) {
        const int fs = (i * 4 + s) * 4;
        if (f0 + fs < F) {
            f32x4 v;
#pragma unroll
            for (int q = 0; q < 4; ++q) v[q] = tile[o * 65 + fs + q];
            *(f32x4*)(ob + fs) = v;
        }
    }
}

extern "C" void kernel_launch(void* const* d_in, const int* in_sizes, int n_in,
                              void* d_out, int out_size, void* d_ws, size_t ws_size,
                              hipStream_t stream)
{
    const float* fe  = (const float*)d_in[0];
    const int*   gm  = (const int*)d_in[1];
    const float* w1  = (const float*)d_in[2];
    const float* b1  = (const float*)d_in[3];
    const float* w2a = (const float*)d_in[4];
    const float* b2a = (const float*)d_in[5];
    const float* w2b = (const float*)d_in[6];
    const float* b2b = (const float*)d_in[7];
    const float* g0  = (const float*)d_in[8];
    const float* be0 = (const float*)d_in[9];
    const float* g1  = (const float*)d_in[10];
    const float* be1 = (const float*)d_in[11];
    const float* g2  = (const float*)d_in[12];
    const float* be2 = (const float*)d_in[13];

    const int B = 4, O = 64;
    const int F = in_sizes[0] / (B * 32);
    const int M = B * F;
    const float invN = 1.0f / (float)M;
    const int nbx = (F + 63) / 64;
    const int nb  = nbx * B;

    // Workspace: bufY bf16 [M][64] + xbuf bf16 [M][64] + partials + weights.
    unsigned short* bufY = (unsigned short*)d_ws;
    unsigned short* xbuf = bufY + (size_t)M * O;
    float* pS   = (float*)(xbuf + (size_t)M * O);       // [64][nb]
    float* pQ   = pS + (size_t)64 * nb;                 // [64][nb]
    float* mr   = pQ + (size_t)64 * nb;                 // [2][64]
    unsigned short* w1b  = (unsigned short*)(mr + 128); // [64][128]
    unsigned short* w2ab = w1b + 64 * 128;              // [64][256]
    unsigned short* w2bb = w2ab + 64 * 256;             // [64][256]
    unsigned short* fe_t = (unsigned short*)d_out;      // [B][F][32] bf16, dead after conv1

    dim3 blk(256);
    dim3 cgrid(nbx, B);
    const int N4 = M * 16;
    dim3 ngrid((N4 + 255) / 256);

    transpose_fe_kernel<<<cgrid, blk, 0, stream>>>(fe, fe_t, F);
    cast_weights_kernel<<<64, 256, 0, stream>>>(w1, w2a, w2b, w1b, w2ab, w2bb);

    // ---- Stage 1 ----
    conv_mfma_kernel<32><<<cgrid, blk, 0, stream>>>(fe_t, gm, w1b, b1, bufY, pS, pQ, nb, F);
    finalize_kernel<<<64, 256, 0, stream>>>(pS, pQ, nb, invN, g0, be0, mr);
    norm_kernel<<<ngrid, blk, 0, stream>>>(bufY, nullptr, mr, xbuf, N4);

    // ---- Stage 2 ----
    conv_mfma_kernel<64><<<cgrid, blk, 0, stream>>>(xbuf, gm, w2ab, b2a, bufY, pS, pQ, nb, F);
    finalize_kernel<<<64, 256, 0, stream>>>(pS, pQ, nb, invN, g1, be1, mr);
    norm_kernel<<<ngrid, blk, 0, stream>>>(bufY, xbuf, mr, xbuf, N4);

    // ---- Stage 3 ----
    conv_mfma_kernel<64><<<cgrid, blk, 0, stream>>>(xbuf, gm, w2bb, b2b, bufY, pS, pQ, nb, F);
    finalize_kernel<<<64, 256, 0, stream>>>(pS, pQ, nb, invN, g2, be2, mr);
    norm_transpose_kernel<<<cgrid, blk, 0, stream>>>(bufY, xbuf, mr, (float*)d_out, F);
}